// Round 1
// baseline (105.197 us; speedup 1.0000x reference)
//
#include <hip/hip_runtime.h>

constexpr int NL = 256;   // lights
constexpr int HW = 256;   // H == W

__global__ __launch_bounds__(256)
void lsf_kernel(const float* __restrict__ X,
                const float* __restrict__ shots,
                const float* __restrict__ lpos,
                float* __restrict__ out, int B)
{
    __shared__ float2 s_lp[NL];
    for (int i = threadIdx.x; i < NL; i += 256)
        s_lp[i] = reinterpret_cast<const float2*>(lpos)[i];
    __syncthreads();

    int b = blockIdx.x * 256 + threadIdx.x;
    if (b >= B) return;

    float4 xv = reinterpret_cast<const float4*>(X)[b];
    float qx = xv.z, qy = xv.w;   // direction coords (X[:,2:4])

    // ---- top-3 nearest lights (ascending distance, ties -> lower index) ----
    float d0 = INFINITY, d1 = INFINITY, d2 = INFINITY;
    int i0 = 0, i1 = 0, i2 = 0;
    for (int i = 0; i < NL; ++i) {
        float2 lp = s_lp[i];
        float dx = qx - lp.x, dy = qy - lp.y;
        float d = dx * dx + dy * dy;
        if (d < d0)      { d2 = d1; i2 = i1; d1 = d0; i1 = i0; d0 = d; i0 = i; }
        else if (d < d1) { d2 = d1; i2 = i1; d1 = d;  i1 = i; }
        else if (d < d2) { d2 = d;  i2 = i; }
    }

    // ---- barycentric weights (matches reference arithmetic) ----
    float2 p0 = s_lp[i0], p1 = s_lp[i1], p2c = s_lp[i2];
    float v0x = p1.x - p0.x,  v0y = p1.y - p0.y;
    float v1x = p2c.x - p0.x, v1y = p2c.y - p0.y;
    float v2x = qx - p0.x,    v2y = qy - p0.y;
    float d00 = v0x * v0x + v0y * v0y;
    float d11 = v1x * v1x + v1y * v1y;
    float d01 = v0x * v1x + v0y * v1y;
    float d20 = v2x * v0x + v2y * v0y;
    float d21 = v2x * v1x + v2y * v1y;
    float denom = d00 * d11 - d01 * d01;
    float v = (d11 * d20 - d01 * d21) / denom;
    float w = (d00 * d21 - d01 * d20) / denom;
    float u = 1.0f - v - w;
    bool outside = (u < 0.f) || (v < 0.f) || (w < 0.f) ||
                   (u != u) || (v != v) || (w != w);
    float w0, w1, w2;
    if (outside) {
        float t = d20 / d00;
        t = fminf(fmaxf(t, 0.f), 1.f);
        w0 = 1.f - t; w1 = t; w2 = 0.f;
    } else {
        w0 = u; w1 = v; w2 = w;
    }

    // ---- bilinear sample coords (align_corners=True, border clamp) ----
    float px = fminf(fmaxf((xv.x + 1.f) * 0.5f * (HW - 1), 0.f), (float)(HW - 1));
    float py = fminf(fmaxf((xv.y + 1.f) * 0.5f * (HW - 1), 0.f), (float)(HW - 1));
    int x0 = (int)floorf(px), y0 = (int)floorf(py);
    int x1 = min(x0 + 1, HW - 1), y1 = min(y0 + 1, HW - 1);
    float wx = px - (float)x0, wy = py - (float)y0;
    float w00 = (1.f - wy) * (1.f - wx), w01 = (1.f - wy) * wx;
    float w10 = wy * (1.f - wx),         w11 = wy * wx;

    // ---- gather + weighted accumulate ----
    // z query lands exactly on slice == light index (error <= ~4e-6), so
    // trilinear degenerates to bilinear on that slice.
    int   idx3[3] = { i0, i1, i2 };
    float wk3[3]  = { w0, w1, w2 };
    float acc[3]  = { 0.f, 0.f, 0.f };
    #pragma unroll
    for (int k = 0; k < 3; ++k) {
        const float* base = shots + (size_t)idx3[k] * (3 * HW * HW);
        float wkk = wk3[k];
        #pragma unroll
        for (int c = 0; c < 3; ++c) {
            const float* pl = base + c * (HW * HW);
            const float* r0 = pl + y0 * HW;
            const float* r1 = pl + y1 * HW;
            float col = r0[x0] * w00 + r0[x1] * w01 +
                        r1[x0] * w10 + r1[x1] * w11;
            acc[c] += wkk * col;
        }
    }

    out[(size_t)b * 3 + 0] = acc[0];
    out[(size_t)b * 3 + 1] = acc[1];
    out[(size_t)b * 3 + 2] = acc[2];
}

extern "C" void kernel_launch(void* const* d_in, const int* in_sizes, int n_in,
                              void* d_out, int out_size, void* d_ws, size_t ws_size,
                              hipStream_t stream) {
    const float* X     = (const float*)d_in[0];
    const float* shots = (const float*)d_in[1];
    const float* lpos  = (const float*)d_in[2];
    float* out = (float*)d_out;
    int B = in_sizes[0] / 4;
    int grid = (B + 255) / 256;
    lsf_kernel<<<grid, 256, 0, stream>>>(X, shots, lpos, out, B);
}